// Round 1
// baseline (310.619 us; speedup 1.0000x reference)
//
#include <hip/hip_runtime.h>
#include <math.h>

// Problem constants (from reference)
#define B  8
#define T  16
#define C  64
#define H  56
#define W  56
#define HW (H*W)          // 3136
#define HW4 (HW/4)        // 784
#define DS 8
#define DIN (DS*DS)       // 64
#define DOUT 32
#define BC (B*C)          // 512

// ---------------------------------------------------------------------------
// Kernel 1: adaptive avg pool 56x56 -> 8x8 per (b,t,c) slice.
// pooled layout: [b*C+c][t][64]  (so it is directly `flat` for the attention)
// ---------------------------------------------------------------------------
__global__ __launch_bounds__(256) void pool_kernel(const float* __restrict__ x,
                                                   float* __restrict__ pooled) {
    __shared__ float lds[HW];
    const int bid = blockIdx.x;           // [0, B*T*C)
    const int tid = threadIdx.x;
    const int b = bid >> 10;              // / (T*C)
    const int t = (bid >> 6) & (T - 1);
    const int c = bid & (C - 1);

    // coalesced float4 staging of the 56x56 slice
    const float4* x4 = (const float4*)x + (size_t)bid * HW4;
    float4* l4 = (float4*)lds;
    for (int i = tid; i < HW4; i += 256) l4[i] = x4[i];
    __syncthreads();

    if (tid < 64) {
        const int i = tid >> 3;           // pooled row
        const int j = tid & 7;            // pooled col
        float s = 0.f;
        const int base = (7 * i) * W + 7 * j;
        #pragma unroll
        for (int di = 0; di < 7; ++di) {
            #pragma unroll
            for (int dj = 0; dj < 7; ++dj) s += lds[base + di * W + dj];
        }
        pooled[(((b * C + c) * T) + t) * DIN + tid] = s * (1.0f / 49.0f);
    }
}

// ---------------------------------------------------------------------------
// Kernel 2: per n in [0,512): q = flat@Wq+bq, k = flat@Wk+bk,
// att = softmax(q k^T / 4). Writes att [512][16][16].
// ---------------------------------------------------------------------------
__global__ __launch_bounds__(256) void att_kernel(const float* __restrict__ pooled,
                                                  const float* __restrict__ Wq,
                                                  const float* __restrict__ bq,
                                                  const float* __restrict__ Wk,
                                                  const float* __restrict__ bk,
                                                  float* __restrict__ att_g) {
    __shared__ float flat_s[T * DIN];     // 1024
    __shared__ float wq_s[DIN * DOUT];    // 2048
    __shared__ float wk_s[DIN * DOUT];    // 2048
    __shared__ float qs[T * DOUT];        // 512
    __shared__ float ks[T * DOUT];        // 512
    __shared__ float att_s[T * T];        // 256

    const int n = blockIdx.x;
    const int tid = threadIdx.x;

    for (int e = tid; e < T * DIN; e += 256) flat_s[e] = pooled[n * (T * DIN) + e];
    for (int e = tid; e < DIN * DOUT; e += 256) { wq_s[e] = Wq[e]; wk_s[e] = Wk[e]; }
    __syncthreads();

    // q,k: 512 elements each; thread handles e and e+256
    for (int e = tid; e < T * DOUT; e += 256) {
        const int t = e >> 5;
        const int d = e & 31;
        float sq = bq[d];
        float sk = bk[d];
        #pragma unroll
        for (int kk = 0; kk < DIN; ++kk) {
            const float f = flat_s[t * DIN + kk];
            sq = fmaf(f, wq_s[kk * DOUT + d], sq);
            sk = fmaf(f, wk_s[kk * DOUT + d], sk);
        }
        qs[e] = sq;
        ks[e] = sk;
    }
    __syncthreads();

    // logits: 256 elements, one per thread
    {
        const int tt = tid >> 4;
        const int ss = tid & 15;
        float s = 0.f;
        #pragma unroll
        for (int d = 0; d < DOUT; ++d) s = fmaf(qs[tt * DOUT + d], ks[ss * DOUT + d], s);
        att_s[tid] = s * 0.25f;           // 1/sqrt(16)
    }
    __syncthreads();

    // softmax per row; 16 threads each own a row
    if (tid < T) {
        const int r = tid;
        float m = -INFINITY;
        #pragma unroll
        for (int s = 0; s < T; ++s) m = fmaxf(m, att_s[r * T + s]);
        float e[T];
        float sum = 0.f;
        #pragma unroll
        for (int s = 0; s < T; ++s) { e[s] = __expf(att_s[r * T + s] - m); sum += e[s]; }
        const float inv = 1.0f / sum;
        #pragma unroll
        for (int s = 0; s < T; ++s) att_g[n * (T * T) + r * T + s] = e[s] * inv;
    }
}

// ---------------------------------------------------------------------------
// Kernel 3: out[b,t,c,p] = sum_s att[b*C+c][t][s] * x[b,s,c,p]
// One block per (n, half). Each thread streams float4 pixels, keeps 16
// accumulators (one per t) so every x element is read exactly once.
// ---------------------------------------------------------------------------
__global__ __launch_bounds__(256) void apply_kernel(const float* __restrict__ x,
                                                    const float* __restrict__ att_g,
                                                    float* __restrict__ out) {
    __shared__ float att_s[T * T];
    const int n = blockIdx.x;             // [0,512) = b*C+c
    const int half = blockIdx.y;          // [0,2)
    const int tid = threadIdx.x;
    const int b = n >> 6;
    const int c = n & 63;

    if (tid < T * T) att_s[tid] = att_g[n * (T * T) + tid];
    __syncthreads();

    const float4* x4 = (const float4*)x;
    float4* o4 = (float4*)out;
    const int p_begin = half * (HW4 / 2);         // 0 or 392
    const int p_end = p_begin + (HW4 / 2);

    for (int p4 = p_begin + tid; p4 < p_end; p4 += 256) {
        float4 acc[T];
        #pragma unroll
        for (int t = 0; t < T; ++t) acc[t] = make_float4(0.f, 0.f, 0.f, 0.f);

        #pragma unroll
        for (int s = 0; s < T; ++s) {
            const float4 xv = x4[((size_t)(b * T + s) * C + c) * HW4 + p4];
            #pragma unroll
            for (int t = 0; t < T; ++t) {
                const float a = att_s[t * T + s];   // uniform across lanes (broadcast)
                acc[t].x = fmaf(a, xv.x, acc[t].x);
                acc[t].y = fmaf(a, xv.y, acc[t].y);
                acc[t].z = fmaf(a, xv.z, acc[t].z);
                acc[t].w = fmaf(a, xv.w, acc[t].w);
            }
        }
        #pragma unroll
        for (int t = 0; t < T; ++t)
            o4[((size_t)(b * T + t) * C + c) * HW4 + p4] = acc[t];
    }
}

extern "C" void kernel_launch(void* const* d_in, const int* in_sizes, int n_in,
                              void* d_out, int out_size, void* d_ws, size_t ws_size,
                              hipStream_t stream) {
    const float* x  = (const float*)d_in[0];
    const float* Wq = (const float*)d_in[1];
    const float* bq = (const float*)d_in[2];
    const float* Wk = (const float*)d_in[3];
    const float* bk = (const float*)d_in[4];
    float* out = (float*)d_out;

    float* pooled = (float*)d_ws;                         // 512*16*64 = 524288 floats
    float* att_g  = pooled + (size_t)BC * T * DIN;        // 512*256  = 131072 floats

    pool_kernel<<<dim3(B * T * C), dim3(256), 0, stream>>>(x, pooled);
    att_kernel<<<dim3(BC), dim3(256), 0, stream>>>(pooled, Wq, bq, Wk, bk, att_g);
    apply_kernel<<<dim3(BC, 2), dim3(256), 0, stream>>>(x, att_g, out);
}